// Round 5
// baseline (1383.697 us; speedup 1.0000x reference)
//
#include <hip/hip_runtime.h>
#include <math.h>

// x: (8, 32, 64, 64, 64) fp32 ; weight: (32cin, 32cout, 3,3,3) ; bias,scale: (32,)
// pooled: (8, 32, 32, 32, 32) in d_ws ; S[256] after pooled in d_ws
// out: (8, 32, 64, 64, 64) fp32

constexpr int CIN_CHUNK = 8;

// ---------------- Pass 1: avg-pool 2x2x2 (+ zero the softmax sums) ----------------
__global__ void pool_kernel(const float* __restrict__ x, float* __restrict__ p,
                            float* __restrict__ S) {
    if (blockIdx.x == 0 && threadIdx.x < 256) S[threadIdx.x] = 0.f;
    int n = blockIdx.x * 256 + threadIdx.x;   // 0 .. 2^21-1
    int wg = n & 7;                            // w'-group (4 outputs)
    int h = (n >> 3) & 31;
    int d = (n >> 8) & 31;
    int bc = n >> 13;                          // b*32+c, 0..255
    const float* xb = x + (((size_t)(bc * 64 + 2 * d) * 64 + 2 * h) * 64 + 8 * wg);
    float4 a0 = *(const float4*)(xb);
    float4 a1 = *(const float4*)(xb + 4);
    float4 b0 = *(const float4*)(xb + 64);
    float4 b1 = *(const float4*)(xb + 68);
    float4 c0 = *(const float4*)(xb + 4096);
    float4 c1 = *(const float4*)(xb + 4100);
    float4 d0 = *(const float4*)(xb + 4160);
    float4 d1 = *(const float4*)(xb + 4164);
    float4 o;
    o.x = (a0.x + a0.y + b0.x + b0.y + c0.x + c0.y + d0.x + d0.y) * 0.125f;
    o.y = (a0.z + a0.w + b0.z + b0.w + c0.z + c0.w + d0.z + d0.w) * 0.125f;
    o.z = (a1.x + a1.y + b1.x + b1.y + c1.x + c1.y + d1.x + d1.y) * 0.125f;
    o.w = (a1.z + a1.w + b1.z + b1.w + c1.z + c1.w + d1.z + d1.w) * 0.125f;
    *(float4*)(p + (size_t)n * 4) = o;
}

// ---------------- Pass 2: conv-transpose + bias + clamp + exp + partial sums ------
// Block: 512 thr = 8 waves. Wave = 4x4x4 pooled cube (one lane per position).
// Each lane: 8 output-parity siblings x 4 couts (cout = wave + 8g) -> acc[32].
// Taps reach inputs {d',d'+1} only (upper halo), so tile halo is 5x5x5.
__global__ __launch_bounds__(512, 4)
void convt_kernel(const float* __restrict__ P, const float* __restrict__ W,
                  const float* __restrict__ bias, float* __restrict__ out,
                  float* __restrict__ S) {
    __shared__ float Pl[CIN_CHUNK][128];       // idx = d0*25 + h0*5 + w0 (125 used)
    __shared__ float Wl[CIN_CHUNK][32][28];    // [cin][cout][tap], 27 used

    const int t = blockIdx.x;                  // 0..511 tile
    const int b = blockIdx.y;
    const int tW4 = (t & 7) * 4;
    const int tH4 = ((t >> 3) & 7) * 4;
    const int tD4 = (t >> 6) * 4;
    const int tid = threadIdx.x;
    const int wave = tid >> 6;
    const int lane = tid & 63;
    const int wq = lane & 3;
    const int hq = (lane >> 2) & 3;
    const int dq = lane >> 4;
    const int pidx = dq * 25 + hq * 5 + wq;

    float acc[32];
#pragma unroll
    for (int i = 0; i < 32; ++i) acc[i] = 0.f;

    for (int cc = 0; cc < 32; cc += CIN_CHUNK) {
        __syncthreads();
        // stage P: CIN_CHUNK x 5x5x5 = 1000 words, zero upper halo
        for (int i = tid; i < CIN_CHUNK * 125; i += 512) {
            int c = i / 125;
            int r = i - c * 125;
            int d0 = r / 25;
            int r2 = r - d0 * 25;
            int h0 = r2 / 5;
            int w0 = r2 - h0 * 5;
            int gd = tD4 + d0, gh = tH4 + h0, gw = tW4 + w0;
            float v = 0.f;
            if (gd < 32 && gh < 32 && gw < 32)
                v = P[(((size_t)(b * 32 + cc + c) * 32 + gd) * 32 + gh) * 32 + gw];
            Pl[c][r] = v;
        }
        // stage W: contiguous src, stride-28 dst rows
        for (int i = tid; i < CIN_CHUNK * 864; i += 512) {
            int q = i / 27;
            int tt = i - q * 27;
            (&Wl[0][0][0])[q * 28 + tt] = W[cc * 864 + i];
        }
        __syncthreads();

#pragma unroll 2
        for (int c = 0; c < CIN_CHUNK; ++c) {
            const float* pb = &Pl[c][pidx];
            float p000 = pb[0], p001 = pb[1];
            float p010 = pb[5], p011 = pb[6];
            float p100 = pb[25], p101 = pb[26];
            float p110 = pb[30], p111 = pb[31];
#pragma unroll
            for (int g = 0; g < 4; ++g) {
                const float* wr = &Wl[c][wave + 8 * g][0];  // wave-uniform: broadcast
#pragma unroll
                for (int kd = 0; kd < 3; ++kd) {
                    const int pd = (kd == 1) ? 0 : 1;
                    const int dd = (kd == 0) ? 1 : 0;
#pragma unroll
                    for (int kh = 0; kh < 3; ++kh) {
                        const int ph = (kh == 1) ? 0 : 1;
                        const int dh = (kh == 0) ? 1 : 0;
#pragma unroll
                        for (int kw = 0; kw < 3; ++kw) {
                            const int pw = (kw == 1) ? 0 : 1;
                            const int dw = (kw == 0) ? 1 : 0;
                            float pv;
                            if (dd) { pv = dh ? (dw ? p111 : p110)
                                              : (dw ? p101 : p100); }
                            else    { pv = dh ? (dw ? p011 : p010)
                                              : (dw ? p001 : p000); }
                            acc[g * 8 + pd * 4 + ph * 2 + pw] +=
                                wr[kd * 9 + kh * 3 + kw] * pv;
                        }
                    }
                }
            }
        }
    }

    // ---- epilogue: bias, clamp, exp, store, softmax partial sums ----
    const int gd = tD4 + dq, gh = tH4 + hq, gw = tW4 + wq;
#pragma unroll
    for (int g = 0; g < 4; ++g) {
        const int cout = wave + 8 * g;
        const float bv = bias[cout];
        float lsum = 0.f;
        float* ob = out + (((size_t)(b * 32 + cout) * 64 + 2 * gd) * 64 + 2 * gh) * 64
                        + 2 * gw;
#pragma unroll
        for (int pd = 0; pd < 2; ++pd) {
#pragma unroll
            for (int ph = 0; ph < 2; ++ph) {
                float e0 = __expf(fminf(fmaxf(acc[g * 8 + pd * 4 + ph * 2 + 0] + bv, 0.f), 1.f));
                float e1 = __expf(fminf(fmaxf(acc[g * 8 + pd * 4 + ph * 2 + 1] + bv, 0.f), 1.f));
                lsum += e0 + e1;
                *(float2*)(ob + (size_t)pd * 4096 + ph * 64) = make_float2(e0, e1);
            }
        }
#pragma unroll
        for (int off = 1; off < 64; off <<= 1) lsum += __shfl_xor(lsum, off, 64);
        if (lane == 0) atomicAdd(&S[b * 32 + cout], lsum);
    }
}

// ---------------- Pass 3: out *= scale[c] / S[b,c] --------------------------------
__global__ void scale_kernel(float* __restrict__ out, const float* __restrict__ S,
                             const float* __restrict__ scale) {
    const int bc = blockIdx.y;
    const float m = scale[bc & 31] / S[bc];
    float4* p = (float4*)out + (size_t)bc * 65536 + blockIdx.x * 1024 + threadIdx.x;
#pragma unroll
    for (int k = 0; k < 4; ++k) {
        float4 v = p[k * 256];
        v.x *= m; v.y *= m; v.z *= m; v.w *= m;
        p[k * 256] = v;
    }
}

extern "C" void kernel_launch(void* const* d_in, const int* in_sizes, int n_in,
                              void* d_out, int out_size, void* d_ws, size_t ws_size,
                              hipStream_t stream) {
    const float* x     = (const float*)d_in[0];
    const float* W     = (const float*)d_in[1];
    const float* bias  = (const float*)d_in[2];
    const float* scale = (const float*)d_in[3];
    float* out = (float*)d_out;
    float* pooled = (float*)d_ws;                    // 32 MiB
    float* S = (float*)d_ws + 8 * 32 * 32768;        // 256 floats

    pool_kernel<<<8192, 256, 0, stream>>>(x, pooled, S);
    convt_kernel<<<dim3(512, 8), 512, 0, stream>>>(pooled, W, bias, out, S);
    scale_kernel<<<dim3(64, 256), 256, 0, stream>>>(out, S, scale);
}

// Round 6
// 1035.239 us; speedup vs baseline: 1.3366x; 1.3366x over previous
//
#include <hip/hip_runtime.h>
#include <math.h>

// x: (8, 32, 64, 64, 64) fp32 ; weight: (32cin, 32cout, 3,3,3) ; bias,scale: (32,)
// pooled: (8, 32, 32, 32, 32) in d_ws ; S[256] after pooled in d_ws
// out: (8, 32, 64, 64, 64) fp32

// ---------------- Pass 1: avg-pool 2x2x2 (+ zero the softmax sums) ----------------
__global__ void pool_kernel(const float* __restrict__ x, float* __restrict__ p,
                            float* __restrict__ S) {
    if (blockIdx.x == 0 && threadIdx.x < 256) S[threadIdx.x] = 0.f;
    int n = blockIdx.x * 256 + threadIdx.x;   // 0 .. 2^21-1
    int wg = n & 7;                            // w'-group (4 outputs)
    int h = (n >> 3) & 31;
    int d = (n >> 8) & 31;
    int bc = n >> 13;                          // b*32+c
    const float* xb = x + (((size_t)(bc * 64 + 2 * d) * 64 + 2 * h) * 64 + 8 * wg);
    float4 a0 = *(const float4*)(xb);
    float4 a1 = *(const float4*)(xb + 4);
    float4 b0 = *(const float4*)(xb + 64);
    float4 b1 = *(const float4*)(xb + 68);
    float4 c0 = *(const float4*)(xb + 4096);
    float4 c1 = *(const float4*)(xb + 4100);
    float4 d0 = *(const float4*)(xb + 4160);
    float4 d1 = *(const float4*)(xb + 4164);
    float4 o;
    o.x = (a0.x + a0.y + b0.x + b0.y + c0.x + c0.y + d0.x + d0.y) * 0.125f;
    o.y = (a0.z + a0.w + b0.z + b0.w + c0.z + c0.w + d0.z + d0.w) * 0.125f;
    o.z = (a1.x + a1.y + b1.x + b1.y + c1.x + c1.y + d1.x + d1.y) * 0.125f;
    o.w = (a1.z + a1.w + b1.z + b1.w + c1.z + c1.w + d1.z + d1.w) * 0.125f;
    *(float4*)(p + (size_t)n * 4) = o;
}

// ---------------- Pass 2: conv-transpose + bias + clamp + exp + partial sums ------
// Grid: (128 tiles, 4 cout-groups, 8 batch). Block 256 thr = 4 waves.
// Tile: pooled d x h x w = 2 x 8 x 16 (one thread per pooled pos), halo 3 x 9 x 17.
// cout is BLOCK-UNIFORM (cg0 + pair loop) -> weight loads are scalar (s_load),
// FMAs are v_fmac(acc, v_p, s_w). Thread owns 8 parity outputs x 2 couts.
constexpr int SW = 20;            // LDS w-stride (words)
constexpr int SD = 180;           // 9*SW
constexpr int SC = 540;           // 3*SD
constexpr int CHUNK = 16;

__global__ __launch_bounds__(256, 4)
void convt_kernel(const float* __restrict__ P, const float* __restrict__ W,
                  const float* __restrict__ bias, float* __restrict__ out,
                  float* __restrict__ S) {
    __shared__ float Pl[CHUNK * SC];   // 34560 B

    const int bx = blockIdx.x;
    const int tw = bx & 1, th = (bx >> 1) & 3, td = bx >> 3;   // tiles: w2 h4 d16
    const int cg0 = blockIdx.y * 8;
    const int b = blockIdx.z;
    const int tid = threadIdx.x;
    const int w = tid & 15, h = (tid >> 4) & 7, d = tid >> 7;

    const float* lp = &Pl[d * SD + h * SW + w];
    const int gd2 = 2 * (td * 2 + d), gh2 = 2 * (th * 8 + h), gw2 = 2 * (tw * 16 + w);

    for (int gp = 0; gp < 4; ++gp) {
        const int coutA = cg0 + 2 * gp;          // block-uniform
        float aA[8], aB[8];
#pragma unroll
        for (int i = 0; i < 8; ++i) { aA[i] = 0.f; aB[i] = 0.f; }

        for (int cc = 0; cc < 32; cc += CHUNK) {
            __syncthreads();
            // ---- stage pooled tile: CHUNK x 3 x 9 rows of 17 words (zero halo) ----
            for (int rid = tid; rid < CHUNK * 27; rid += 256) {
                int c = rid / 27;
                int r = rid - c * 27;
                int d0 = r / 9;
                int h0 = r - d0 * 9;
                int gd = td * 2 + d0, gh = th * 8 + h0;
                float* dst = &Pl[c * SC + d0 * SD + h0 * SW];
                if (gd < 32 && gh < 32) {
                    const float* src = P +
                        ((((size_t)(b * 32 + cc + c) * 32 + gd) * 32 + gh) * 32 + tw * 16);
                    float4 v0 = ((const float4*)src)[0];
                    float4 v1 = ((const float4*)src)[1];
                    float4 v2 = ((const float4*)src)[2];
                    float4 v3 = ((const float4*)src)[3];
                    ((float4*)dst)[0] = v0;
                    ((float4*)dst)[1] = v1;
                    ((float4*)dst)[2] = v2;
                    ((float4*)dst)[3] = v3;
                    dst[16] = (tw == 0) ? src[16] : 0.f;   // w-halo word
                } else {
                    float4 z = make_float4(0.f, 0.f, 0.f, 0.f);
                    ((float4*)dst)[0] = z;
                    ((float4*)dst)[1] = z;
                    ((float4*)dst)[2] = z;
                    ((float4*)dst)[3] = z;
                    dst[16] = 0.f;
                }
            }
            __syncthreads();

            for (int c = 0; c < CHUNK; ++c) {
                const float* lc = lp + c * SC;        // immediate-offset reads below
                const float p000 = lc[0];
                const float p001 = lc[1];
                const float p010 = lc[SW];
                const float p011 = lc[SW + 1];
                const float p100 = lc[SD];
                const float p101 = lc[SD + 1];
                const float p110 = lc[SD + SW];
                const float p111 = lc[SD + SW + 1];
                const float* WA = W + (size_t)((cc + c) * 32 + coutA) * 27;  // uniform
#pragma unroll
                for (int kd = 0; kd < 3; ++kd) {
                    const int pd = (kd == 1) ? 0 : 1;
                    const int dd = (kd == 0) ? 1 : 0;
#pragma unroll
                    for (int kh = 0; kh < 3; ++kh) {
                        const int ph = (kh == 1) ? 0 : 1;
                        const int dh = (kh == 0) ? 1 : 0;
#pragma unroll
                        for (int kw = 0; kw < 3; ++kw) {
                            const int pw = (kw == 1) ? 0 : 1;
                            const int dw = (kw == 0) ? 1 : 0;
                            const int t = kd * 9 + kh * 3 + kw;
                            const int tgt = pd * 4 + ph * 2 + pw;
                            const float pv =
                                dd ? (dh ? (dw ? p111 : p110) : (dw ? p101 : p100))
                                   : (dh ? (dw ? p011 : p010) : (dw ? p001 : p000));
                            aA[tgt] = fmaf(pv, WA[t], aA[tgt]);        // s_w operand
                            aB[tgt] = fmaf(pv, WA[27 + t], aB[tgt]);   // cout+1
                        }
                    }
                }
            }
        }

        // ---- epilogue: bias, clamp, exp, 128B-run stores, softmax partials ----
        const float bvA = bias[coutA];
        const float bvB = bias[coutA + 1];
        float lsA = 0.f, lsB = 0.f;
        float* obA = out + ((((size_t)(b * 32 + coutA) * 64 + gd2) * 64 + gh2) * 64 + gw2);
        float* obB = obA + 262144;
#pragma unroll
        for (int pd = 0; pd < 2; ++pd) {
#pragma unroll
            for (int ph = 0; ph < 2; ++ph) {
                const int o = pd * 4 + ph * 2;
                const size_t off = (size_t)pd * 4096 + ph * 64;
                float e0 = __expf(fminf(fmaxf(aA[o] + bvA, 0.f), 1.f));
                float e1 = __expf(fminf(fmaxf(aA[o + 1] + bvA, 0.f), 1.f));
                lsA += e0 + e1;
                *(float2*)(obA + off) = make_float2(e0, e1);
                float f0 = __expf(fminf(fmaxf(aB[o] + bvB, 0.f), 1.f));
                float f1 = __expf(fminf(fmaxf(aB[o + 1] + bvB, 0.f), 1.f));
                lsB += f0 + f1;
                *(float2*)(obB + off) = make_float2(f0, f1);
            }
        }
#pragma unroll
        for (int off = 1; off < 64; off <<= 1) {
            lsA += __shfl_xor(lsA, off, 64);
            lsB += __shfl_xor(lsB, off, 64);
        }
        if ((tid & 63) == 0) {
            atomicAdd(&S[b * 32 + coutA], lsA);
            atomicAdd(&S[b * 32 + coutA + 1], lsB);
        }
    }
}

// ---------------- Pass 3: out *= scale[c] / S[b,c] --------------------------------
__global__ void scale_kernel(float* __restrict__ out, const float* __restrict__ S,
                             const float* __restrict__ scale) {
    const int bc = blockIdx.y;
    const float m = scale[bc & 31] / S[bc];
    float4* p = (float4*)out + (size_t)bc * 65536 + blockIdx.x * 1024 + threadIdx.x;
#pragma unroll
    for (int k = 0; k < 4; ++k) {
        float4 v = p[k * 256];
        v.x *= m; v.y *= m; v.z *= m; v.w *= m;
        p[k * 256] = v;
    }
}

extern "C" void kernel_launch(void* const* d_in, const int* in_sizes, int n_in,
                              void* d_out, int out_size, void* d_ws, size_t ws_size,
                              hipStream_t stream) {
    const float* x     = (const float*)d_in[0];
    const float* W     = (const float*)d_in[1];
    const float* bias  = (const float*)d_in[2];
    const float* scale = (const float*)d_in[3];
    float* out = (float*)d_out;
    float* pooled = (float*)d_ws;                    // 32 MiB
    float* S = (float*)d_ws + 8 * 32 * 32768;        // 256 floats

    pool_kernel<<<8192, 256, 0, stream>>>(x, pooled, S);
    convt_kernel<<<dim3(128, 4, 8), 256, 0, stream>>>(pooled, W, bias, out, S);
    scale_kernel<<<dim3(64, 256), 256, 0, stream>>>(out, S, scale);
}

// Round 7
// 961.226 us; speedup vs baseline: 1.4395x; 1.0770x over previous
//
#include <hip/hip_runtime.h>
#include <math.h>

// x: (8,32,64,64,64) fp32 ; weight: (32cin,32cout,3,3,3) ; bias,scale: (32,)
// d_ws: pooled (8,32,32,32,32) | S[256] | Wp[32*32*40]
// out: (8,32,64,64,64) fp32

constexpr int PSW = 20;    // P LDS row stride (words; 16 used, b128-quad-spread)
constexpr int PSD = 180;   // 9 rows per d-plane
constexpr int PSC = 540;   // per-cin P words (3 planes)
constexpr int QSC = 108;   // per-cin Q words (27 rows x 4 halo words)
constexpr int CHUNK = 8;
constexpr int WROW = 40;   // packed weight stride per (cout,cin)

// ---------------- Pass 0: repack weights into row-grouped layout -------------------
// Wp[cout][cin][40]: taps grouped by LDS-row (dd,dh): g00(12)@0 g01(6)@16 g10(6)@24
// g11(3)@32, each group in (kd,kh,kw) nested order, 16B-aligned groups.
__global__ void prep_kernel(const float* __restrict__ W, float* __restrict__ Wp) {
    int idx = blockIdx.x * 256 + threadIdx.x;
    if (idx >= 1024) return;
    int co = idx >> 5, ci = idx & 31;
    const float* src = W + (ci * 32 + co) * 27;
    float* dst = Wp + (size_t)(co * 32 + ci) * WROW;
    int pos[4] = {0, 16, 24, 32};
    for (int kd = 0; kd < 3; ++kd)
        for (int kh = 0; kh < 3; ++kh)
            for (int kw = 0; kw < 3; ++kw) {
                int r = (kd == 0) * 2 + (kh == 0);
                dst[pos[r]++] = src[kd * 9 + kh * 3 + kw];
            }
}

// ---------------- Pass 1: avg-pool 2x2x2 (+ zero the softmax sums) ----------------
__global__ void pool_kernel(const float* __restrict__ x, float* __restrict__ p,
                            float* __restrict__ S) {
    if (blockIdx.x == 0 && threadIdx.x < 256) S[threadIdx.x] = 0.f;
    int n = blockIdx.x * 256 + threadIdx.x;
    int wg = n & 7;
    int h = (n >> 3) & 31;
    int d = (n >> 8) & 31;
    int bc = n >> 13;
    const float* xb = x + (((size_t)(bc * 64 + 2 * d) * 64 + 2 * h) * 64 + 8 * wg);
    float4 a0 = *(const float4*)(xb);
    float4 a1 = *(const float4*)(xb + 4);
    float4 b0 = *(const float4*)(xb + 64);
    float4 b1 = *(const float4*)(xb + 68);
    float4 c0 = *(const float4*)(xb + 4096);
    float4 c1 = *(const float4*)(xb + 4100);
    float4 d0 = *(const float4*)(xb + 4160);
    float4 d1 = *(const float4*)(xb + 4164);
    float4 o;
    o.x = (a0.x + a0.y + b0.x + b0.y + c0.x + c0.y + d0.x + d0.y) * 0.125f;
    o.y = (a0.z + a0.w + b0.z + b0.w + c0.z + c0.w + d0.z + d0.w) * 0.125f;
    o.z = (a1.x + a1.y + b1.x + b1.y + c1.x + c1.y + d1.x + d1.y) * 0.125f;
    o.w = (a1.z + a1.w + b1.z + b1.w + c1.z + c1.w + d1.z + d1.w) * 0.125f;
    *(float4*)(p + (size_t)n * 4) = o;
}

// ---------------- Pass 2: conv-transpose + bias + clamp + exp + partial sums ------
// Grid (128 tiles, 4 cout-groups, 8 batch), 512 thr = 8 waves. Wave = 1 cout.
// Lane (d2,h8,w4): 4 w-outputs x 8 parities = acc[32]. P: b128 window, Q: halo.
#define TAP(WV, PD, PH, PW, DW) do {                                   \
    acc[((PD)*4+(PH)*2+(PW))*4+0] = fmaf(pr[0+(DW)], (WV), acc[((PD)*4+(PH)*2+(PW))*4+0]); \
    acc[((PD)*4+(PH)*2+(PW))*4+1] = fmaf(pr[1+(DW)], (WV), acc[((PD)*4+(PH)*2+(PW))*4+1]); \
    acc[((PD)*4+(PH)*2+(PW))*4+2] = fmaf(pr[2+(DW)], (WV), acc[((PD)*4+(PH)*2+(PW))*4+2]); \
    acc[((PD)*4+(PH)*2+(PW))*4+3] = fmaf(pr[3+(DW)], (WV), acc[((PD)*4+(PH)*2+(PW))*4+3]); \
} while (0)

template <bool PACKED>
__global__ __launch_bounds__(512, 6)
void convt_kernel(const float* __restrict__ P, const float* __restrict__ Wsrc,
                  const float* __restrict__ bias, float* __restrict__ out,
                  float* __restrict__ S) {
    __shared__ float Pl[CHUNK * PSC];   // 17280 B
    __shared__ float Ql[CHUNK * QSC];   //  3456 B

    const int bx = blockIdx.x;
    const int tw = bx & 1, th = (bx >> 1) & 3, td = bx >> 3;
    const int b = blockIdx.z;
    const int tid = threadIdx.x;
    const int cout = (blockIdx.y << 3) + (tid >> 6);
    const int lane = tid & 63;
    const int w4 = lane & 3, h = (lane >> 2) & 7, d = lane >> 5;

    float acc[32];
#pragma unroll
    for (int i = 0; i < 32; ++i) acc[i] = 0.f;

    for (int cc = 0; cc < 32; cc += CHUNK) {
        __syncthreads();
        // stage: 216 rows; P gets words 0..15, Q gets words {4,8,12,16} (halo col)
        for (int rid = tid; rid < CHUNK * 27; rid += 512) {
            int c = rid / 27, r = rid - c * 27;
            int dz = r / 9, hz = r - dz * 9;
            int gd = td * 2 + dz, gh = th * 8 + hz;
            float4 v0, v1, v2, v3;
            float hv;
            if (gd < 32 && gh < 32) {
                const float* src = P +
                    ((((size_t)(b * 32 + cc + c) * 32 + gd) * 32 + gh) * 32 + tw * 16);
                v0 = ((const float4*)src)[0];
                v1 = ((const float4*)src)[1];
                v2 = ((const float4*)src)[2];
                v3 = ((const float4*)src)[3];
                hv = (tw == 0) ? src[16] : 0.f;
            } else {
                v0 = v1 = v2 = v3 = make_float4(0.f, 0.f, 0.f, 0.f);
                hv = 0.f;
            }
            float* pdst = &Pl[c * PSC + dz * PSD + hz * PSW];
            ((float4*)pdst)[0] = v0;
            ((float4*)pdst)[1] = v1;
            ((float4*)pdst)[2] = v2;
            ((float4*)pdst)[3] = v3;
            *(float4*)&Ql[c * QSC + r * 4] = make_float4(v1.x, v2.x, v3.x, hv);
        }
        __syncthreads();

#pragma unroll 2
        for (int c = 0; c < CHUNK; ++c) {
            const float* pc = &Pl[c * PSC + d * PSD + h * PSW + w4 * 4];
            const float* qc = &Ql[c * QSC + (9 * d + h) * 4 + w4];
            float w00[12], w01[6], w10[6], w11[3];
            if (PACKED) {
                const float* wr = Wsrc + ((size_t)cout * 32 + cc + c) * WROW;
                float4 a = ((const float4*)wr)[0], e = ((const float4*)wr)[1],
                       f = ((const float4*)wr)[2], g = ((const float4*)wr)[4],
                       k = ((const float4*)wr)[6];
                float2 m = *(const float2*)(wr + 20), n = *(const float2*)(wr + 28),
                       o = *(const float2*)(wr + 32);
                w00[0]=a.x; w00[1]=a.y; w00[2]=a.z; w00[3]=a.w;
                w00[4]=e.x; w00[5]=e.y; w00[6]=e.z; w00[7]=e.w;
                w00[8]=f.x; w00[9]=f.y; w00[10]=f.z; w00[11]=f.w;
                w01[0]=g.x; w01[1]=g.y; w01[2]=g.z; w01[3]=g.w; w01[4]=m.x; w01[5]=m.y;
                w10[0]=k.x; w10[1]=k.y; w10[2]=k.z; w10[3]=k.w; w10[4]=n.x; w10[5]=n.y;
                w11[0]=o.x; w11[1]=o.y; w11[2]=wr[34];
            } else {
                const float* wr = Wsrc + ((size_t)((cc + c) * 32) + cout) * 27;
                w00[0]=wr[12]; w00[1]=wr[13]; w00[2]=wr[14]; w00[3]=wr[15];
                w00[4]=wr[16]; w00[5]=wr[17]; w00[6]=wr[21]; w00[7]=wr[22];
                w00[8]=wr[23]; w00[9]=wr[24]; w00[10]=wr[25]; w00[11]=wr[26];
                w01[0]=wr[9]; w01[1]=wr[10]; w01[2]=wr[11];
                w01[3]=wr[18]; w01[4]=wr[19]; w01[5]=wr[20];
                w10[0]=wr[3]; w10[1]=wr[4]; w10[2]=wr[5];
                w10[3]=wr[6]; w10[4]=wr[7]; w10[5]=wr[8];
                w11[0]=wr[0]; w11[1]=wr[1]; w11[2]=wr[2];
            }
            {   // row (dd=0, dh=0): taps kd in {1,2}, kh in {1,2}
                float4 pm = *(const float4*)pc;
                float pr[5] = {pm.x, pm.y, pm.z, pm.w, qc[0]};
                TAP(w00[0],0,0,1,1); TAP(w00[1],0,0,0,0); TAP(w00[2],0,0,1,0);
                TAP(w00[3],0,1,1,1); TAP(w00[4],0,1,0,0); TAP(w00[5],0,1,1,0);
                TAP(w00[6],1,0,1,1); TAP(w00[7],1,0,0,0); TAP(w00[8],1,0,1,0);
                TAP(w00[9],1,1,1,1); TAP(w00[10],1,1,0,0); TAP(w00[11],1,1,1,0);
            }
            {   // row (dd=0, dh=1): kd in {1,2}, kh=0
                float4 pm = *(const float4*)(pc + PSW);
                float pr[5] = {pm.x, pm.y, pm.z, pm.w, qc[4]};
                TAP(w01[0],0,1,1,1); TAP(w01[1],0,1,0,0); TAP(w01[2],0,1,1,0);
                TAP(w01[3],1,1,1,1); TAP(w01[4],1,1,0,0); TAP(w01[5],1,1,1,0);
            }
            {   // row (dd=1, dh=0): kd=0, kh in {1,2}
                float4 pm = *(const float4*)(pc + PSD);
                float pr[5] = {pm.x, pm.y, pm.z, pm.w, qc[36]};
                TAP(w10[0],1,0,1,1); TAP(w10[1],1,0,0,0); TAP(w10[2],1,0,1,0);
                TAP(w10[3],1,1,1,1); TAP(w10[4],1,1,0,0); TAP(w10[5],1,1,1,0);
            }
            {   // row (dd=1, dh=1): kd=0, kh=0
                float4 pm = *(const float4*)(pc + PSD + PSW);
                float pr[5] = {pm.x, pm.y, pm.z, pm.w, qc[40]};
                TAP(w11[0],1,1,1,1); TAP(w11[1],1,1,0,0); TAP(w11[2],1,1,1,0);
            }
        }
    }

    // ---- epilogue: bias, clamp, exp, coalesced stores, softmax partials ----
    const float bv = bias[cout];
    float lsum = 0.f;
    const int ow0 = tw * 32 + w4 * 8;
    float* ob = out + (size_t)(b * 32 + cout) * 262144;
#pragma unroll
    for (int pd = 0; pd < 2; ++pd) {
        const int od = 2 * (td * 2 + d) + pd;
#pragma unroll
        for (int ph = 0; ph < 2; ++ph) {
            const int oh = 2 * (th * 8 + h) + ph;
            float e[8];
#pragma unroll
            for (int i = 0; i < 4; ++i)
#pragma unroll
                for (int pw = 0; pw < 2; ++pw) {
                    float y = acc[(pd * 4 + ph * 2 + pw) * 4 + i] + bv;
                    y = fminf(fmaxf(y, 0.f), 1.f);
                    float ev = __expf(y);
                    lsum += ev;
                    e[2 * i + pw] = ev;
                }
            float* dst = ob + (size_t)od * 4096 + oh * 64 + ow0;
            *(float4*)dst = make_float4(e[0], e[1], e[2], e[3]);
            *(float4*)(dst + 4) = make_float4(e[4], e[5], e[6], e[7]);
        }
    }
#pragma unroll
    for (int off = 1; off < 64; off <<= 1) lsum += __shfl_xor(lsum, off, 64);
    if (lane == 0) atomicAdd(&S[b * 32 + cout], lsum);
}

// ---------------- Pass 3: out *= scale[c] / S[b,c] --------------------------------
__global__ void scale_kernel(float* __restrict__ out, const float* __restrict__ S,
                             const float* __restrict__ scale) {
    const int bc = blockIdx.y;
    const float m = scale[bc & 31] / S[bc];
    float4* p = (float4*)out + (size_t)bc * 65536 + blockIdx.x * 1024 + threadIdx.x;
#pragma unroll
    for (int k = 0; k < 4; ++k) {
        float4 v = p[k * 256];
        v.x *= m; v.y *= m; v.z *= m; v.w *= m;
        p[k * 256] = v;
    }
}

extern "C" void kernel_launch(void* const* d_in, const int* in_sizes, int n_in,
                              void* d_out, int out_size, void* d_ws, size_t ws_size,
                              hipStream_t stream) {
    const float* x     = (const float*)d_in[0];
    const float* W     = (const float*)d_in[1];
    const float* bias  = (const float*)d_in[2];
    const float* scale = (const float*)d_in[3];
    float* out = (float*)d_out;
    float* pooled = (float*)d_ws;                      // 32 MiB
    float* S  = (float*)d_ws + 8 * 32 * 32768;         // 256 floats
    float* Wp = S + 256;                               // 32*32*40 floats = 160 KiB

    const size_t need = (size_t)(8 * 32 * 32768 + 256 + 32 * 32 * WROW) * 4;
    const bool packed = ws_size >= need;

    pool_kernel<<<8192, 256, 0, stream>>>(x, pooled, S);
    if (packed) {
        prep_kernel<<<4, 256, 0, stream>>>(W, Wp);
        convt_kernel<true><<<dim3(128, 4, 8), 512, 0, stream>>>(pooled, Wp, bias, out, S);
    } else {
        convt_kernel<false><<<dim3(128, 4, 8), 512, 0, stream>>>(pooled, W, bias, out, S);
    }
    scale_kernel<<<dim3(64, 256), 256, 0, stream>>>(out, S, scale);
}

// Round 9
// 924.198 us; speedup vs baseline: 1.4972x; 1.0401x over previous
//
#include <hip/hip_runtime.h>
#include <math.h>

// x: (8,32,64,64,64) fp32 ; weight: (32cin,32cout,3,3,3) ; bias,scale: (32,)
// d_ws: pooled (8,32,32,32,32) | S[256] | Wp[32*32*40]
// out: (8,32,64,64,64) fp32

constexpr int PSW = 16;    // P LDS row stride (words) = 64B: bank-perfect b128 reads
constexpr int PSD = 144;   // 9 rows per d-plane
constexpr int PSC = 432;   // per-cin P words (3 planes)
constexpr int QSC = 108;   // per-cin Q words (27 rows x 4 halo words)
constexpr int CHUNK = 8;
constexpr int WROW = 40;   // packed weight stride per (cout,cin)

// ---------------- Pass 0: repack weights into row-grouped layout -------------------
// Wp[cout][cin][40]: taps grouped by LDS-row (dd,dh): g00(12)@0 g01(6)@16 g10(6)@24
// g11(3)@32, each group in (kd,kh,kw) nested order, 16B-aligned groups.
__global__ void prep_kernel(const float* __restrict__ W, float* __restrict__ Wp) {
    int idx = blockIdx.x * 256 + threadIdx.x;
    if (idx >= 1024) return;
    int co = idx >> 5, ci = idx & 31;
    const float* src = W + (ci * 32 + co) * 27;
    float* dst = Wp + (size_t)(co * 32 + ci) * WROW;
    int pos[4] = {0, 16, 24, 32};
    for (int kd = 0; kd < 3; ++kd)
        for (int kh = 0; kh < 3; ++kh)
            for (int kw = 0; kw < 3; ++kw) {
                int r = (kd == 0) * 2 + (kh == 0);
                dst[pos[r]++] = src[kd * 9 + kh * 3 + kw];
            }
}

// ---------------- Pass 1: avg-pool 2x2x2 (+ zero the softmax sums) ----------------
__global__ void pool_kernel(const float* __restrict__ x, float* __restrict__ p,
                            float* __restrict__ S) {
    if (blockIdx.x == 0 && threadIdx.x < 256) S[threadIdx.x] = 0.f;
    int n = blockIdx.x * 256 + threadIdx.x;
    int wg = n & 7;
    int h = (n >> 3) & 31;
    int d = (n >> 8) & 31;
    int bc = n >> 13;
    const float* xb = x + (((size_t)(bc * 64 + 2 * d) * 64 + 2 * h) * 64 + 8 * wg);
    float4 a0 = *(const float4*)(xb);
    float4 a1 = *(const float4*)(xb + 4);
    float4 b0 = *(const float4*)(xb + 64);
    float4 b1 = *(const float4*)(xb + 68);
    float4 c0 = *(const float4*)(xb + 4096);
    float4 c1 = *(const float4*)(xb + 4100);
    float4 d0 = *(const float4*)(xb + 4160);
    float4 d1 = *(const float4*)(xb + 4164);
    float4 o;
    o.x = (a0.x + a0.y + b0.x + b0.y + c0.x + c0.y + d0.x + d0.y) * 0.125f;
    o.y = (a0.z + a0.w + b0.z + b0.w + c0.z + c0.w + d0.z + d0.w) * 0.125f;
    o.z = (a1.x + a1.y + b1.x + b1.y + c1.x + c1.y + d1.x + d1.y) * 0.125f;
    o.w = (a1.z + a1.w + b1.z + b1.w + c1.z + c1.w + d1.z + d1.w) * 0.125f;
    *(float4*)(p + (size_t)n * 4) = o;
}

// ---------------- Pass 2: conv-transpose + bias + clamp + exp + partial sums ------
// Grid (128 tiles, 4 cout-groups, 8 batch), 512 thr = 8 waves. Wave = 1 cout.
// Lane (d2,h8,w4): 4 w-outputs x 8 parities = acc[32]. P: b128 window, Q: halo.
#define TAP(WV, PD, PH, PW, DW) do {                                   \
    acc[((PD)*4+(PH)*2+(PW))*4+0] = fmaf(pr[0+(DW)], (WV), acc[((PD)*4+(PH)*2+(PW))*4+0]); \
    acc[((PD)*4+(PH)*2+(PW))*4+1] = fmaf(pr[1+(DW)], (WV), acc[((PD)*4+(PH)*2+(PW))*4+1]); \
    acc[((PD)*4+(PH)*2+(PW))*4+2] = fmaf(pr[2+(DW)], (WV), acc[((PD)*4+(PH)*2+(PW))*4+2]); \
    acc[((PD)*4+(PH)*2+(PW))*4+3] = fmaf(pr[3+(DW)], (WV), acc[((PD)*4+(PH)*2+(PW))*4+3]); \
} while (0)

template <bool PACKED>
__global__ __launch_bounds__(512, 6)
void convt_kernel(const float* __restrict__ P, const float* __restrict__ Wsrc,
                  const float* __restrict__ bias, float* __restrict__ out,
                  float* __restrict__ S) {
    __shared__ float Pl[CHUNK * PSC];   // 13824 B
    __shared__ float Ql[CHUNK * QSC];   //  3456 B

    const int bx = blockIdx.x;
    const int tw = bx & 1, th = (bx >> 1) & 3, td = bx >> 3;
    const int b = blockIdx.z;
    const int tid = threadIdx.x;
    const int cout = (blockIdx.y << 3) + (tid >> 6);
    const int lane = tid & 63;
    const int w4 = lane & 3, h = (lane >> 2) & 7, d = lane >> 5;

    float acc[32];
#pragma unroll
    for (int i = 0; i < 32; ++i) acc[i] = 0.f;

    for (int cc = 0; cc < 32; cc += CHUNK) {
        __syncthreads();
        // stage quad-granular: uid = c*108 + r*4 + q. Write banks: 16(c+r)+4q
        // -> every 8 consecutive lanes tile all 32 banks (conflict-free b128).
        for (int uid = tid; uid < CHUNK * 108; uid += 512) {
            int q = uid & 3;
            int t1 = uid >> 2;               // c*27 + r
            int c = t1 / 27;
            int r = t1 - c * 27;
            int dz = r / 9;
            int hz = r - dz * 9;
            int gd = td * 2 + dz, gh = th * 8 + hz;
            float4 v = make_float4(0.f, 0.f, 0.f, 0.f);
            float hv = 0.f;
            if (gd < 32 && gh < 32) {
                const float* src = P +
                    ((((size_t)(b * 32 + cc + c) * 32 + gd) * 32 + gh) * 32
                     + tw * 16 + 4 * q);
                v = *(const float4*)src;
                if (q == 3 && tw == 0) hv = src[4];   // row word 16 (w-halo)
            }
            *(float4*)&Pl[c * PSC + r * PSW + 4 * q] = v;
            if (q) Ql[c * QSC + 4 * r + (q - 1)] = v.x;
            if (q == 3) Ql[c * QSC + 4 * r + 3] = hv;
        }
        __syncthreads();

#pragma unroll 2
        for (int c = 0; c < CHUNK; ++c) {
            const float* pc = &Pl[c * PSC + d * PSD + h * PSW + w4 * 4];
            const float* qc = &Ql[c * QSC + (9 * d + h) * 4 + w4];
            float w00[12], w01[6], w10[6], w11[3];
            if (PACKED) {
                const float* wr = Wsrc + ((size_t)cout * 32 + cc + c) * WROW;
                float4 a = ((const float4*)wr)[0], e = ((const float4*)wr)[1],
                       f = ((const float4*)wr)[2], g = ((const float4*)wr)[4],
                       k = ((const float4*)wr)[6];
                float2 m = *(const float2*)(wr + 20), n = *(const float2*)(wr + 28),
                       o = *(const float2*)(wr + 32);
                w00[0]=a.x; w00[1]=a.y; w00[2]=a.z; w00[3]=a.w;
                w00[4]=e.x; w00[5]=e.y; w00[6]=e.z; w00[7]=e.w;
                w00[8]=f.x; w00[9]=f.y; w00[10]=f.z; w00[11]=f.w;
                w01[0]=g.x; w01[1]=g.y; w01[2]=g.z; w01[3]=g.w; w01[4]=m.x; w01[5]=m.y;
                w10[0]=k.x; w10[1]=k.y; w10[2]=k.z; w10[3]=k.w; w10[4]=n.x; w10[5]=n.y;
                w11[0]=o.x; w11[1]=o.y; w11[2]=wr[34];
            } else {
                const float* wr = Wsrc + ((size_t)((cc + c) * 32) + cout) * 27;
                w00[0]=wr[12]; w00[1]=wr[13]; w00[2]=wr[14]; w00[3]=wr[15];
                w00[4]=wr[16]; w00[5]=wr[17]; w00[6]=wr[21]; w00[7]=wr[22];
                w00[8]=wr[23]; w00[9]=wr[24]; w00[10]=wr[25]; w00[11]=wr[26];
                w01[0]=wr[9]; w01[1]=wr[10]; w01[2]=wr[11];
                w01[3]=wr[18]; w01[4]=wr[19]; w01[5]=wr[20];
                w10[0]=wr[3]; w10[1]=wr[4]; w10[2]=wr[5];
                w10[3]=wr[6]; w10[4]=wr[7]; w10[5]=wr[8];
                w11[0]=wr[0]; w11[1]=wr[1]; w11[2]=wr[2];
            }
            {   // row (dd=0, dh=0): taps kd in {1,2}, kh in {1,2}
                float4 pm = *(const float4*)pc;
                float pr[5] = {pm.x, pm.y, pm.z, pm.w, qc[0]};
                TAP(w00[0],0,0,1,1); TAP(w00[1],0,0,0,0); TAP(w00[2],0,0,1,0);
                TAP(w00[3],0,1,1,1); TAP(w00[4],0,1,0,0); TAP(w00[5],0,1,1,0);
                TAP(w00[6],1,0,1,1); TAP(w00[7],1,0,0,0); TAP(w00[8],1,0,1,0);
                TAP(w00[9],1,1,1,1); TAP(w00[10],1,1,0,0); TAP(w00[11],1,1,1,0);
            }
            {   // row (dd=0, dh=1): kd in {1,2}, kh=0
                float4 pm = *(const float4*)(pc + PSW);
                float pr[5] = {pm.x, pm.y, pm.z, pm.w, qc[4]};
                TAP(w01[0],0,1,1,1); TAP(w01[1],0,1,0,0); TAP(w01[2],0,1,1,0);
                TAP(w01[3],1,1,1,1); TAP(w01[4],1,1,0,0); TAP(w01[5],1,1,1,0);
            }
            {   // row (dd=1, dh=0): kd=0, kh in {1,2}
                float4 pm = *(const float4*)(pc + PSD);
                float pr[5] = {pm.x, pm.y, pm.z, pm.w, qc[36]};
                TAP(w10[0],1,0,1,1); TAP(w10[1],1,0,0,0); TAP(w10[2],1,0,1,0);
                TAP(w10[3],1,1,1,1); TAP(w10[4],1,1,0,0); TAP(w10[5],1,1,1,0);
            }
            {   // row (dd=1, dh=1): kd=0, kh=0
                float4 pm = *(const float4*)(pc + PSD + PSW);
                float pr[5] = {pm.x, pm.y, pm.z, pm.w, qc[40]};
                TAP(w11[0],1,1,1,1); TAP(w11[1],1,1,0,0); TAP(w11[2],1,1,1,0);
            }
        }
    }

    // ---- epilogue: bias, clamp, exp, shfl-transposed 64B-run stores, partials ----
    const float bv = bias[cout];
    float lsum = 0.f;
    float* ob = out + (size_t)(b * 32 + cout) * 262144;
    const int base = lane & ~3;
    const int s0 = base | (w4 >> 1);
    const int s1 = base | (2 + (w4 >> 1));
    const bool oddq = (w4 & 1) != 0;
#pragma unroll
    for (int pd = 0; pd < 2; ++pd) {
        const int od = 2 * (td * 2 + d) + pd;
#pragma unroll
        for (int ph = 0; ph < 2; ++ph) {
            const int oh = 2 * (th * 8 + h) + ph;
            float lo[4], hi[4];
#pragma unroll
            for (int i = 0; i < 4; ++i)
#pragma unroll
                for (int pw = 0; pw < 2; ++pw) {
                    float y = acc[(pd * 4 + ph * 2 + pw) * 4 + i] + bv;
                    y = fminf(fmaxf(y, 0.f), 1.f);
                    float ev = __expf(y);
                    lsum += ev;
                    const int j = 2 * i + pw;
                    if (j < 4) lo[j] = ev; else hi[j - 4] = ev;
                }
            // lane w4 holds output quads {2w4 (lo), 2w4+1 (hi)} of the 32-float span;
            // re-own so instr k writes quad 4k+w4 -> 64B contiguous per 4 lanes.
            float q0[4], q1[4];
#pragma unroll
            for (int j = 0; j < 4; ++j) {
                float a0 = __shfl(lo[j], s0, 64);
                float b0 = __shfl(hi[j], s0, 64);
                q0[j] = oddq ? b0 : a0;
                float a1 = __shfl(lo[j], s1, 64);
                float b1 = __shfl(hi[j], s1, 64);
                q1[j] = oddq ? b1 : a1;
            }
            float* dst = ob + (size_t)od * 4096 + oh * 64 + tw * 32;
            *(float4*)(dst + 4 * w4) = make_float4(q0[0], q0[1], q0[2], q0[3]);
            *(float4*)(dst + 16 + 4 * w4) = make_float4(q1[0], q1[1], q1[2], q1[3]);
        }
    }
#pragma unroll
    for (int off = 1; off < 64; off <<= 1) lsum += __shfl_xor(lsum, off, 64);
    if (lane == 0) atomicAdd(&S[b * 32 + cout], lsum);
}

// ---------------- Pass 3: out *= scale[c] / S[b,c] --------------------------------
__global__ void scale_kernel(float* __restrict__ out, const float* __restrict__ S,
                             const float* __restrict__ scale) {
    const int bc = blockIdx.y;
    const float m = scale[bc & 31] / S[bc];
    float4* p = (float4*)out + (size_t)bc * 65536 + blockIdx.x * 1024 + threadIdx.x;
#pragma unroll
    for (int k = 0; k < 4; ++k) {
        float4 v = p[k * 256];
        v.x *= m; v.y *= m; v.z *= m; v.w *= m;
        p[k * 256] = v;
    }
}

extern "C" void kernel_launch(void* const* d_in, const int* in_sizes, int n_in,
                              void* d_out, int out_size, void* d_ws, size_t ws_size,
                              hipStream_t stream) {
    const float* x     = (const float*)d_in[0];
    const float* W     = (const float*)d_in[1];
    const float* bias  = (const float*)d_in[2];
    const float* scale = (const float*)d_in[3];
    float* out = (float*)d_out;
    float* pooled = (float*)d_ws;                      // 32 MiB
    float* S  = (float*)d_ws + 8 * 32 * 32768;         // 256 floats
    float* Wp = S + 256;                               // 32*32*40 floats = 160 KiB

    const size_t need = (size_t)(8 * 32 * 32768 + 256 + 32 * 32 * WROW) * 4;
    const bool packed = ws_size >= need;

    pool_kernel<<<8192, 256, 0, stream>>>(x, pooled, S);
    if (packed) {
        prep_kernel<<<4, 256, 0, stream>>>(W, Wp);
        convt_kernel<true><<<dim3(128, 4, 8), 512, 0, stream>>>(pooled, Wp, bias, out, S);
    } else {
        convt_kernel<false><<<dim3(128, 4, 8), 512, 0, stream>>>(pooled, W, bias, out, S);
    }
    scale_kernel<<<dim3(64, 256), 256, 0, stream>>>(out, S, scale);
}